// Round 8
// baseline (473.204 us; speedup 1.0000x reference)
//
#include <hip/hip_runtime.h>
#include <hip/hip_bf16.h>

// ---------------------------------------------------------------------------
// GCN stack: 3 graphs x 3 layers (256->256->128->64), final scalar = sum/64.
// Math: with h' = (x@W) * dis[row],
//   out[i] = relu( dis[i] * (h'[i] + sum_{e: dst=i} h'[src[e]]) + b )
// R15: L1 GEMM retiled to the proven L2 geometry (WM=2,WN=2, 256 thr,
// BN=128, grid.x=2; 8 blocks/CU at 18.4KB LDS) with B staged via
// global_load_lds (linear LDS); A keeps sync fp32->bf16 VGPR staging
// generalized to 2 chunks/thread. Attacks the 88us/8%-MfmaUtil L1 GEMM.
// R14: bf16 GEMMs (L2/L3) fully global_load_lds width-16, linear [row][32]
// LDS. R11: gather unroll-8 + uint2 CSR idx; bucket_p2 4-aligns CSR.
// R10: 16B dwordx4 gather loads. R8: 2-pass LDS counting-sort CSR build.
// ---------------------------------------------------------------------------

typedef unsigned short ushort_t;
typedef unsigned int uint_t;
typedef unsigned char uchar_t;
typedef __attribute__((ext_vector_type(8))) short v8s;   // 8 bf16
typedef __attribute__((ext_vector_type(4))) float v4f;   // MFMA accum
typedef __attribute__((ext_vector_type(2))) float v2f;

struct FP3 { const float* a; const float* b; const float* c; };
struct IP3 { const int* a; const int* b; const int* c; };

#define BKT_SHIFT 9            // 512 nodes per bucket
#define BKT_NODES 512
#define NBKT_MAX 128           // supports Nn <= 65536 (ushort csr constraint)
#define BKT_CAP 12288          // edge slots per bucket region (mean 8192 @ E=800k)
#define P1_CH 4096             // edges per pass-1 block

static __device__ __forceinline__ ushort_t f2bf(float f) {
    uint_t u = __float_as_uint(f);
    u += 0x7fffu + ((u >> 16) & 1u);   // RNE
    return (ushort_t)(u >> 16);
}
static __device__ __forceinline__ uint_t pack2(float a, float b) {
    return (uint_t)f2bf(a) | ((uint_t)f2bf(b) << 16);
}

// async 16B global->LDS (no VGPR round-trip); dest must be linear in lane order
static __device__ __forceinline__ void gload_lds16(const ushort_t* g, ushort_t* l) {
    __builtin_amdgcn_global_load_lds(g, l, 16, 0, 0);
}

// permutation within each 64-block: stored pos q holds actual col P64(q)
static __device__ __forceinline__ int P64(int q) {
    return (q & ~63) | (((q & 3) << 4) | ((q & 63) >> 2));
}

// fp8 e4m3fn encode, RNE, clamp (fallback path).
static __device__ __forceinline__ uint_t f2fp8(float f) {
    uint_t u = __float_as_uint(f);
    uint_t s = (u >> 24) & 0x80u;
    uint_t a = u & 0x7fffffffu;
    uint_t r;
    if (a >= 0x43E00000u) {
        r = 0x7Eu;
    } else if (a < 0x3C800000u) {
        r = (uint_t)(int)rintf(__uint_as_float(a) * 512.0f);
    } else {
        uint_t t = a + 0x7FFFFu + ((a >> 20) & 1u);
        r = (t >> 20) - 960u;
        if (r > 0x7Eu) r = 0x7Eu;
    }
    return s | r;
}
static __device__ __forceinline__ uint_t pack_fp8x4(float a, float b, float c, float d) {
#if __has_builtin(__builtin_amdgcn_cvt_pk_fp8_f32)
    int w = 0;
    w = __builtin_amdgcn_cvt_pk_fp8_f32(a, b, w, false);   // bytes 0,1
    w = __builtin_amdgcn_cvt_pk_fp8_f32(c, d, w, true);    // bytes 2,3
    return (uint_t)w;
#else
    return f2fp8(a) | (f2fp8(b) << 8) | (f2fp8(c) << 16) | (f2fp8(d) << 24);
#endif
}
static __device__ __forceinline__ float fp8f(uint_t b) {
    uint_t t = (b & 0x7Fu) << 20;
    float f = __uint_as_float(t) * 0x1.0p+120f;
    return __uint_as_float(__float_as_uint(f) | ((b & 0x80u) << 24));
}
static __device__ __forceinline__ float4 fp84cvt(uint_t w) {
    float4 f;
#if __has_builtin(__builtin_amdgcn_cvt_pk_f32_fp8)
    v2f lo = __builtin_amdgcn_cvt_pk_f32_fp8((int)w, false);
    v2f hi = __builtin_amdgcn_cvt_pk_f32_fp8((int)w, true);
    f.x = lo[0]; f.y = lo[1]; f.z = hi[0]; f.w = hi[1];
#else
    f.x = fp8f(w & 0xffu); f.y = fp8f((w >> 8) & 0xffu);
    f.z = fp8f((w >> 16) & 0xffu); f.w = fp8f(w >> 24);
#endif
    return f;
}
static __device__ __forceinline__ float4 load_fp84(const uchar_t* p) {
    return fp84cvt(*(const uint_t*)p);
}
// accumulate 16 fp8 (one uint4) into a[16]
static __device__ __forceinline__ void acc16(float* a, uint4 w) {
    float4 f;
    f = fp84cvt(w.x); a[0]+=f.x; a[1]+=f.y; a[2]+=f.z; a[3]+=f.w;
    f = fp84cvt(w.y); a[4]+=f.x; a[5]+=f.y; a[6]+=f.z; a[7]+=f.w;
    f = fp84cvt(w.z); a[8]+=f.x; a[9]+=f.y; a[10]+=f.z; a[11]+=f.w;
    f = fp84cvt(w.w); a[12]+=f.x; a[13]+=f.y; a[14]+=f.z; a[15]+=f.w;
}

// ---------------------------------------------------------------------------
__global__ __launch_bounds__(256) void zero_small_k(int* p, int n) {
    int i = blockIdx.x * 256 + threadIdx.x;
    if (i < n) p[i] = 0;
}

// Weight transpose+convert (Wt2/Wt3 k-permuted) + permuted bias copies.
__global__ __launch_bounds__(256) void wt_all_k(
    const float* __restrict__ W1, const float* __restrict__ W2, const float* __restrict__ W3,
    const float* __restrict__ b1, const float* __restrict__ b2, const float* __restrict__ b3,
    ushort_t* __restrict__ Wt1, ushort_t* __restrict__ Wt2, ushort_t* __restrict__ Wt3,
    float* __restrict__ b1p, float* __restrict__ b2p, float* __restrict__ b3p) {
    int i = blockIdx.x * 256 + threadIdx.x;
    if (i < 65536) {
        int k = i >> 8, n = i & 255;
        Wt1[n * 256 + k] = f2bf(W1[i]);            // A of GEMM-1 (X) unpermuted
    } else if (i < 98304) {
        int j = i - 65536; int k = j >> 7, n = j & 127;   // k' in [0,256)
        Wt2[n * 256 + k] = f2bf(W2[P64(k) * 128 + n]);
    } else if (i < 106496) {
        int j = i - 98304; int k = j >> 6, n = j & 63;    // k' in [0,128)
        Wt3[n * 128 + k] = f2bf(W3[P64(k) * 64 + n]);
    } else if (i < 106752) {
        int c = i - 106496; b1p[c] = b1[P64(c)];
    } else if (i < 106880) {
        int c = i - 106752; b2p[c] = b2[P64(c)];
    } else if (i < 106944) {
        int c = i - 106880; b3p[c] = b3[P64(c)];
    }
}

// ---------------------------------------------------------------------------
// Pass 1: LDS counting sort of a 4096-edge chunk by bucket (dst>>9), then
// coalesced run-writes into fixed-capacity bucket regions of bkt[].
// Record: src | dstlow<<16 | b<<25  (src<65536, dstlow<512, b<128).
// ---------------------------------------------------------------------------
__global__ __launch_bounds__(256) void bucket_p1_k(IP3 ei, int E, int nbkt,
    int* __restrict__ bcur, uint_t* __restrict__ bkt)
{
    int g = blockIdx.y;
    const int* eb = g == 0 ? ei.a : (g == 1 ? ei.b : ei.c);
    __shared__ uint_t srt[P1_CH];
    __shared__ int cntL[NBKT_MAX], offsL[NBKT_MAX], fillL[NBKT_MAX], gbaseL[NBKT_MAX];
    const int t = threadIdx.x;
    if (t < NBKT_MAX) { cntL[t] = 0; fillL[t] = 0; }
    __syncthreads();

    const int cb = blockIdx.x * P1_CH;
    const int ne = (cb + P1_CH <= E) ? P1_CH : (E - cb);
    uint_t rec[16];
    int rb[16];
    #pragma unroll
    for (int j = 0; j < 16; ++j) {
        int e = cb + j * 256 + t;
        rb[j] = -1;
        if (e < E) {
            int s = eb[e], d = eb[E + e];
            int b = d >> BKT_SHIFT;
            rb[j] = b;
            rec[j] = (uint_t)s | ((uint_t)(d & (BKT_NODES - 1)) << 16) | ((uint_t)b << 25);
            atomicAdd(&cntL[b], 1);
        }
    }
    __syncthreads();

    // exclusive scan over NBKT_MAX bins, wave 0 (2 bins/lane)
    if (t < 64) {
        int i0 = 2 * t, i1 = 2 * t + 1;
        int c0 = cntL[i0], c1 = cntL[i1];
        int s = c0 + c1, x = s;
        #pragma unroll
        for (int off = 1; off < 64; off <<= 1) {
            int y = __shfl_up(x, off);
            if (t >= off) x += y;
        }
        offsL[i0] = x - s;
        offsL[i1] = x - c1;
    }
    __syncthreads();
    if (t < nbkt) gbaseL[t] = atomicAdd(&bcur[g * nbkt + t], cntL[t]);
    __syncthreads();

    // scatter records into LDS-sorted order
    #pragma unroll
    for (int j = 0; j < 16; ++j) {
        if (rb[j] >= 0) {
            int p = offsL[rb[j]] + atomicAdd(&fillL[rb[j]], 1);
            srt[p] = rec[j];
        }
    }
    __syncthreads();

    // coalesced run-copy to global bucket regions
    for (int i = t; i < ne; i += 256) {
        uint_t r = srt[i];
        int b = r >> 25;
        int glob = gbaseL[b] + (i - offsL[b]);
        if (glob < BKT_CAP)
            bkt[((long)(g * nbkt + b)) * BKT_CAP + glob] = r;
    }
}

// ---------------------------------------------------------------------------
// Pass 2: one block per (graph,bucket). Count per-node degrees in LDS, block
// scan over CEIL4(cnt) so every node's CSR start is 4-ushort (8B) aligned
// (enables uint2 index loads in the gathers); emit rs/cnt/dis coalesced;
// stage the bucket's CSR segment in LDS and flush with uint4 stores.
// ---------------------------------------------------------------------------
__global__ __launch_bounds__(256) void bucket_p2_k(
    const uint_t* __restrict__ bkt, const int* __restrict__ bcur,
    ushort_t* __restrict__ csr, int* __restrict__ rs, int* __restrict__ cnt,
    float* __restrict__ dis, int Nn, int nbkt)
{
    const int b = blockIdx.x, g = blockIdx.y;
    const int r = g * nbkt + b;
    __shared__ __align__(16) ushort_t csrL[BKT_CAP];
    __shared__ int cntL[BKT_NODES], offsL[BKT_NODES], fillL[BKT_NODES];
    __shared__ int wsum[4];
    const int t = threadIdx.x;
    cntL[t] = 0; cntL[t + 256] = 0;
    fillL[t] = 0; fillL[t + 256] = 0;
    __syncthreads();

    int nE = bcur[r];
    if (nE > BKT_CAP) nE = BKT_CAP;
    const uint_t* src = bkt + (long)r * BKT_CAP;

    for (int i = t; i < nE; i += 256)
        atomicAdd(&cntL[(src[i] >> 16) & (BKT_NODES - 1)], 1);
    __syncthreads();

    // exclusive scan over 512 CEIL4'd counters (2/thread, adjacent pair)
    int c0 = cntL[2 * t], c1 = cntL[2 * t + 1];
    int a0 = (c0 + 3) & ~3, a1 = (c1 + 3) & ~3;
    int s = a0 + a1, x = s;
    const int lane = t & 63, wid = t >> 6;
    #pragma unroll
    for (int off = 1; off < 64; off <<= 1) {
        int y = __shfl_up(x, off);
        if (lane >= off) x += y;
    }
    if (lane == 63) wsum[wid] = x;
    __syncthreads();
    int we = 0;
    #pragma unroll
    for (int w = 0; w < 4; ++w) if (w < wid) we += wsum[w];
    x += we;
    offsL[2 * t] = x - s;
    offsL[2 * t + 1] = x - a1;
    const int padTot = wsum[0] + wsum[1] + wsum[2] + wsum[3];
    __syncthreads();

    // rs / cnt / dis (coalesced)
    const int rbase = r * BKT_CAP;
    for (int nl = t; nl < BKT_NODES; nl += 256) {
        int node = (b << BKT_SHIFT) + nl;
        if (node < Nn) {
            int gi = g * Nn + node;
            int c = cntL[nl];
            rs[gi] = rbase + offsL[nl];
            cnt[gi] = c;
            dis[gi] = rsqrtf((float)c + 1.0f);
        }
    }

    // build CSR segment in LDS (guard: pad may push past cap at ~40 sigma)
    for (int i = t; i < nE; i += 256) {
        uint_t rr = src[i];
        int dl = (rr >> 16) & (BKT_NODES - 1);
        int p = offsL[dl] + atomicAdd(&fillL[dl], 1);
        if (p < BKT_CAP) csrL[p] = (ushort_t)(rr & 0xffffu);
    }
    __syncthreads();

    // flush CSR segment coalesced (16B chunks over padded extent)
    ushort_t* dst = csr + (long)rbase;
    int nF = padTot < BKT_CAP ? padTot : BKT_CAP;
    int nF8 = (nF + 7) & ~7;
    if (nF8 > BKT_CAP) nF8 = BKT_CAP;
    for (int i = t * 8; i < nF8; i += 2048)
        *(uint4*)(dst + i) = *(const uint4*)(csrL + i);
}

// ---------------------------------------------------------------------------
// MFMA GEMM over M = Bc*Nn rows: H8[m][c'] = fp8(D[m][P64(c')] * dis[m]).
// AFP32 (L1): sync fp32->bf16 VGPR staging for A (NCA chunks/thread, LDA=40
// pad); B staged via global_load_lds into linear [row][32] LDS.
// bf16 (L2/L3): both A and B via global_load_lds, linear [row][32] LDS
// (chunk c at byte c*16 = wave-uniform base + lane*16).
// Direct permuted global store (C/D: col=lane&15, row=quad*4+reg).
// ---------------------------------------------------------------------------
template<int WM, int WN, bool AFP32, int K_>
__global__ __launch_bounds__(WM * WN * 64) void gemm_mfma_k(
    FP3 xp, const ushort_t* __restrict__ Ab,
    const ushort_t* __restrict__ Wt, const float* __restrict__ dis,
    uchar_t* __restrict__ out8, int M, int N, int Nn)
{
    constexpr int BM = WM * 64, BN = WN * 64, NT = WM * WN * 64;
    constexpr int LDA = AFP32 ? 40 : 32;   // A rows: pad (sync write) vs linear
    constexpr int LDB = 32;                // B rows: linear (gload_lds)
    constexpr int NCA = (BM * 4) / NT;     // 16B chunks per thread (A)
    constexpr int NCB = (BN * 4) / NT;     // 16B chunks per thread (B)
    __shared__ __align__(16) ushort_t As[BM * LDA];
    __shared__ __align__(16) ushort_t Bs[BN * LDB];

    const int tid  = threadIdx.x;
    const int lane = tid & 63;
    const int wave = tid >> 6;
    const int quad = lane >> 4, l16 = lane & 15;
    const int wm = wave / WN, wn = wave % WN;
    const int tile_m = blockIdx.y * BM, tile_n = blockIdx.x * BN;

    v4f acc[4][4];
    #pragma unroll
    for (int i = 0; i < 4; ++i)
        #pragma unroll
        for (int j = 0; j < 4; ++j)
            acc[i][j] = (v4f){0.f, 0.f, 0.f, 0.f};

    const float* Xrow[AFP32 ? NCA : 1];
    const int akc = (tid & 3) * 8;         // k-offset within 32-chunk (NT%4==0)
    if constexpr (AFP32) {
        #pragma unroll
        for (int i = 0; i < NCA; ++i) {
            int r = (tid >> 2) + i * (NT / 4);
            int gr = tile_m + r;
            Xrow[i] = nullptr;
            if (gr < M) {
                int lg = gr / Nn;
                int rl = gr - lg * Nn;
                const float* Xg = lg == 0 ? xp.a : (lg == 1 ? xp.b : xp.c);
                Xrow[i] = Xg + (long)rl * K_;
            }
        }
    }

    for (int k0 = 0; k0 < K_; k0 += 32) {
        if constexpr (AFP32) {
            #pragma unroll
            for (int i = 0; i < NCA; ++i) {
                int r = (tid >> 2) + i * (NT / 4);
                uint4 w = make_uint4(0, 0, 0, 0);
                if (Xrow[i]) {
                    float4 f0 = *(const float4*)(Xrow[i] + k0 + akc);
                    float4 f1 = *(const float4*)(Xrow[i] + k0 + akc + 4);
                    w.x = pack2(f0.x, f0.y); w.y = pack2(f0.z, f0.w);
                    w.z = pack2(f1.x, f1.y); w.w = pack2(f1.z, f1.w);
                }
                *(uint4*)&As[r * LDA + akc] = w;
            }
        } else {
            // async direct-to-LDS staging; OOB tail rows (<16) read allocated
            // workspace and only pollute never-stored acc rows.
            #pragma unroll
            for (int i = 0; i < NCA; ++i) {
                int cch = tid + i * NT;
                int r = cch >> 2, kc = (cch & 3) * 8;
                gload_lds16(Ab + (long)(tile_m + r) * K_ + k0 + kc, &As[cch * 8]);
            }
        }
        #pragma unroll
        for (int i = 0; i < NCB; ++i) {
            int cch = tid + i * NT;
            int r = cch >> 2, kc = (cch & 3) * 8;
            gload_lds16(Wt + (long)(tile_n + r) * K_ + k0 + kc, &Bs[cch * 8]);
        }
        __syncthreads();

        v8s a[4], b[4];
        #pragma unroll
        for (int f = 0; f < 4; ++f)
            a[f] = *(const v8s*)&As[(wm * 64 + f * 16 + l16) * LDA + quad * 8];
        #pragma unroll
        for (int f = 0; f < 4; ++f)
            b[f] = *(const v8s*)&Bs[(wn * 64 + f * 16 + l16) * LDB + quad * 8];
        #pragma unroll
        for (int i = 0; i < 4; ++i)
            #pragma unroll
            for (int j = 0; j < 4; ++j)
                acc[i][j] = __builtin_amdgcn_mfma_f32_16x16x32_bf16(a[i], b[j], acc[i][j], 0, 0, 0);
        __syncthreads();
    }

    #pragma unroll
    for (int i = 0; i < 4; ++i) {
        #pragma unroll
        for (int r = 0; r < 4; ++r) {
            int gr = tile_m + wm * 64 + i * 16 + quad * 4 + r;
            if (gr < M) {
                float s = dis[gr];
                uint_t w = pack_fp8x4(acc[i][0][r] * s, acc[i][1][r] * s,
                                      acc[i][2][r] * s, acc[i][3][r] * s);
                *(uint_t*)(out8 + (long)gr * N + tile_n + wn * 64 + l16 * 4) = w;
            }
        }
    }
}

// ---------------------------------------------------------------------------
// Gather + relu. L = F/16 lanes per node, 16B dwordx4 loads, unroll-8 with
// uint2 CSR index loads (node CSR starts are 8B-aligned by bucket_p2).
// OUT[i] = bf16(relu(dis[i]*(H[i] + sum_nbrs H[s]) + bp)); cols permuted.
// ---------------------------------------------------------------------------
template<int F>
__global__ __launch_bounds__(256) void gather_relu_k(
    const uchar_t* __restrict__ H8, ushort_t* __restrict__ OUT,
    const int* __restrict__ rs, const int* __restrict__ cnt,
    const ushort_t* __restrict__ csr, const float* __restrict__ dis,
    const float* __restrict__ bias, int n, int Nn)
{
    constexpr int L = F / 16;          // lanes per node
    constexpr int NPB = 256 / L;
    int node = blockIdx.x * NPB + threadIdx.x / L;
    if (node >= n) return;
    int c = (threadIdx.x % L) * 16;    // col base (fp8: 1 byte per col)
    int base = rs[node];
    int deg  = cnt[node];
    int lg   = node / Nn;
    const uchar_t* Hg = H8 + (long)lg * Nn * F;

    float a[16];
    {
        uint4 w = *(const uint4*)(H8 + (long)node * F + c);   // self-loop
        float4 f;
        f = fp84cvt(w.x); a[0]=f.x; a[1]=f.y; a[2]=f.z; a[3]=f.w;
        f = fp84cvt(w.y); a[4]=f.x; a[5]=f.y; a[6]=f.z; a[7]=f.w;
        f = fp84cvt(w.z); a[8]=f.x; a[9]=f.y; a[10]=f.z; a[11]=f.w;
        f = fp84cvt(w.w); a[12]=f.x; a[13]=f.y; a[14]=f.z; a[15]=f.w;
    }
    int k = 0;
    for (; k + 7 < deg; k += 8) {
        uint2 i0 = *(const uint2*)(csr + base + k);
        uint2 i1 = *(const uint2*)(csr + base + k + 4);
        int s0 = i0.x & 0xffff, s1 = i0.x >> 16;
        int s2 = i0.y & 0xffff, s3 = i0.y >> 16;
        int s4 = i1.x & 0xffff, s5 = i1.x >> 16;
        int s6 = i1.y & 0xffff, s7 = i1.y >> 16;
        uint4 w0 = *(const uint4*)(Hg + (long)s0 * F + c);
        uint4 w1 = *(const uint4*)(Hg + (long)s1 * F + c);
        uint4 w2 = *(const uint4*)(Hg + (long)s2 * F + c);
        uint4 w3 = *(const uint4*)(Hg + (long)s3 * F + c);
        uint4 w4 = *(const uint4*)(Hg + (long)s4 * F + c);
        uint4 w5 = *(const uint4*)(Hg + (long)s5 * F + c);
        uint4 w6 = *(const uint4*)(Hg + (long)s6 * F + c);
        uint4 w7 = *(const uint4*)(Hg + (long)s7 * F + c);
        acc16(a, w0); acc16(a, w1); acc16(a, w2); acc16(a, w3);
        acc16(a, w4); acc16(a, w5); acc16(a, w6); acc16(a, w7);
    }
    for (; k + 3 < deg; k += 4) {
        uint2 i0 = *(const uint2*)(csr + base + k);
        int s0 = i0.x & 0xffff, s1 = i0.x >> 16;
        int s2 = i0.y & 0xffff, s3 = i0.y >> 16;
        uint4 w0 = *(const uint4*)(Hg + (long)s0 * F + c);
        uint4 w1 = *(const uint4*)(Hg + (long)s1 * F + c);
        uint4 w2 = *(const uint4*)(Hg + (long)s2 * F + c);
        uint4 w3 = *(const uint4*)(Hg + (long)s3 * F + c);
        acc16(a, w0); acc16(a, w1); acc16(a, w2); acc16(a, w3);
    }
    for (; k < deg; ++k) {
        int s0 = csr[base + k];
        uint4 w0 = *(const uint4*)(Hg + (long)s0 * F + c);
        acc16(a, w0);
    }
    float di = dis[node];
    const float4* bp = (const float4*)(bias + c);
    float4 b0 = bp[0], b1 = bp[1], b2 = bp[2], b3 = bp[3];
    uint4 o0, o1;
    o0.x = pack2(fmaxf(fmaf(di, a[0],  b0.x), 0.f), fmaxf(fmaf(di, a[1],  b0.y), 0.f));
    o0.y = pack2(fmaxf(fmaf(di, a[2],  b0.z), 0.f), fmaxf(fmaf(di, a[3],  b0.w), 0.f));
    o0.z = pack2(fmaxf(fmaf(di, a[4],  b1.x), 0.f), fmaxf(fmaf(di, a[5],  b1.y), 0.f));
    o0.w = pack2(fmaxf(fmaf(di, a[6],  b1.z), 0.f), fmaxf(fmaf(di, a[7],  b1.w), 0.f));
    o1.x = pack2(fmaxf(fmaf(di, a[8],  b2.x), 0.f), fmaxf(fmaf(di, a[9],  b2.y), 0.f));
    o1.y = pack2(fmaxf(fmaf(di, a[10], b2.z), 0.f), fmaxf(fmaf(di, a[11], b2.w), 0.f));
    o1.z = pack2(fmaxf(fmaf(di, a[12], b3.x), 0.f), fmaxf(fmaf(di, a[13], b3.y), 0.f));
    o1.w = pack2(fmaxf(fmaf(di, a[14], b3.z), 0.f), fmaxf(fmaf(di, a[15], b3.w), 0.f));
    ushort_t* orow = OUT + (long)node * F + c;
    *(uint4*)(orow) = o0;
    *(uint4*)(orow + 8) = o1;
}

// Layer-3: gather + relu + per-block partial sum (permutation-invariant).
// F=64: L=4 lanes/node, 64 nodes/block, unroll-8.
__global__ __launch_bounds__(256) void gather_reduce_k(
    const uchar_t* __restrict__ H8,
    const int* __restrict__ rs, const int* __restrict__ cnt,
    const ushort_t* __restrict__ csr, const float* __restrict__ dis,
    const float* __restrict__ bias, int n, int Nn, float* __restrict__ partial)
{
    constexpr int F = 64, L = 4, NPB = 64;
    int node = blockIdx.x * NPB + threadIdx.x / L;
    int c = (threadIdx.x % L) * 16;
    float val = 0.f;
    if (node < n) {
        int lg = node / Nn;
        const uchar_t* Hg = H8 + (long)lg * Nn * F;
        float a[16];
        {
            uint4 w = *(const uint4*)(H8 + (long)node * F + c);
            float4 f;
            f = fp84cvt(w.x); a[0]=f.x; a[1]=f.y; a[2]=f.z; a[3]=f.w;
            f = fp84cvt(w.y); a[4]=f.x; a[5]=f.y; a[6]=f.z; a[7]=f.w;
            f = fp84cvt(w.z); a[8]=f.x; a[9]=f.y; a[10]=f.z; a[11]=f.w;
            f = fp84cvt(w.w); a[12]=f.x; a[13]=f.y; a[14]=f.z; a[15]=f.w;
        }
        int base = rs[node], deg = cnt[node];
        int k = 0;
        for (; k + 7 < deg; k += 8) {
            uint2 i0 = *(const uint2*)(csr + base + k);
            uint2 i1 = *(const uint2*)(csr + base + k + 4);
            int s0 = i0.x & 0xffff, s1 = i0.x >> 16;
            int s2 = i0.y & 0xffff, s3 = i0.y >> 16;
            int s4 = i1.x & 0xffff, s5 = i1.x >> 16;
            int s6 = i1.y & 0xffff, s7 = i1.y >> 16;
            uint4 w0 = *(const uint4*)(Hg + (long)s0 * F + c);
            uint4 w1 = *(const uint4*)(Hg + (long)s1 * F + c);
            uint4 w2 = *(const uint4*)(Hg + (long)s2 * F + c);
            uint4 w3 = *(const uint4*)(Hg + (long)s3 * F + c);
            uint4 w4 = *(const uint4*)(Hg + (long)s4 * F + c);
            uint4 w5 = *(const uint4*)(Hg + (long)s5 * F + c);
            uint4 w6 = *(const uint4*)(Hg + (long)s6 * F + c);
            uint4 w7 = *(const uint4*)(Hg + (long)s7 * F + c);
            acc16(a, w0); acc16(a, w1); acc16(a, w2); acc16(a, w3);
            acc16(a, w4); acc16(a, w5); acc16(a, w6); acc16(a, w7);
        }
        for (; k + 3 < deg; k += 4) {
            uint2 i0 = *(const uint2*)(csr + base + k);
            int s0 = i0.x & 0xffff, s1 = i0.x >> 16;
            int s2 = i0.y & 0xffff, s3 = i0.y >> 16;
            uint4 w0 = *(const uint4*)(Hg + (long)s0 * F + c);
            uint4 w1 = *(const uint4*)(Hg + (long)s1 * F + c);
            uint4 w2 = *(const uint4*)(Hg + (long)s2 * F + c);
            uint4 w3 = *(const uint4*)(Hg + (long)s3 * F + c);
            acc16(a, w0); acc16(a, w1); acc16(a, w2); acc16(a, w3);
        }
        for (; k < deg; ++k) {
            int s0 = csr[base + k];
            uint4 w0 = *(const uint4*)(Hg + (long)s0 * F + c);
            acc16(a, w0);
        }
        float di = dis[node];
        const float4* bp = (const float4*)(bias + c);
        float4 b0 = bp[0], b1 = bp[1], b2 = bp[2], b3 = bp[3];
        val  = fmaxf(fmaf(di, a[0],  b0.x), 0.f) + fmaxf(fmaf(di, a[1],  b0.y), 0.f)
             + fmaxf(fmaf(di, a[2],  b0.z), 0.f) + fmaxf(fmaf(di, a[3],  b0.w), 0.f)
             + fmaxf(fmaf(di, a[4],  b1.x), 0.f) + fmaxf(fmaf(di, a[5],  b1.y), 0.f)
             + fmaxf(fmaf(di, a[6],  b1.z), 0.f) + fmaxf(fmaf(di, a[7],  b1.w), 0.f)
             + fmaxf(fmaf(di, a[8],  b2.x), 0.f) + fmaxf(fmaf(di, a[9],  b2.y), 0.f)
             + fmaxf(fmaf(di, a[10], b2.z), 0.f) + fmaxf(fmaf(di, a[11], b2.w), 0.f)
             + fmaxf(fmaf(di, a[12], b3.x), 0.f) + fmaxf(fmaf(di, a[13], b3.y), 0.f)
             + fmaxf(fmaf(di, a[14], b3.z), 0.f) + fmaxf(fmaf(di, a[15], b3.w), 0.f);
    }
    #pragma unroll
    for (int off = 32; off > 0; off >>= 1) val += __shfl_down(val, off);
    __shared__ float wsum[4];
    int lane = threadIdx.x & 63, wid = threadIdx.x >> 6;
    if (lane == 0) wsum[wid] = val;
    __syncthreads();
    if (threadIdx.x == 0)
        partial[blockIdx.x] = wsum[0] + wsum[1] + wsum[2] + wsum[3];
}

__global__ __launch_bounds__(1024) void reduce_partials_k(
    const float* __restrict__ partial, int npart, float* __restrict__ out)
{
    float s = 0.f;
    for (int i = threadIdx.x; i < npart; i += 1024) s += partial[i];
    #pragma unroll
    for (int off = 32; off > 0; off >>= 1) s += __shfl_down(s, off);
    __shared__ float wsum[16];
    int lane = threadIdx.x & 63, wid = threadIdx.x >> 6;
    if (lane == 0) wsum[wid] = s;
    __syncthreads();
    if (threadIdx.x == 0) {
        float t = 0.f;
        #pragma unroll
        for (int w = 0; w < 16; ++w) t += wsum[w];
        out[0] = t * (1.0f / 64.0f);
    }
}

extern "C" void kernel_launch(void* const* d_in, const int* in_sizes, int n_in,
                              void* d_out, int out_size, void* d_ws, size_t ws_size,
                              hipStream_t stream) {
    const float* X[3]  = {(const float*)d_in[0], (const float*)d_in[1], (const float*)d_in[2]};
    const int*   EI[3] = {(const int*)d_in[3], (const int*)d_in[4], (const int*)d_in[5]};
    const float* W1 = (const float*)d_in[6];
    const float* b1 = (const float*)d_in[7];
    const float* W2 = (const float*)d_in[8];
    const float* b2 = (const float*)d_in[9];
    const float* W3 = (const float*)d_in[10];
    const float* b3 = (const float*)d_in[11];
    float* out = (float*)d_out;

    const int Nn = in_sizes[0] / 256;   // 50000 (< 65536 for ushort csr)
    const int E  = in_sizes[3] / 2;     // 800000
    const int B  = 3;
    const int nbkt = (Nn + BKT_NODES - 1) >> BKT_SHIFT;   // 98

    // ---- workspace layout (512B-aligned regions) ----
    char* base = (char*)d_ws;
    size_t off = 0;
    auto take = [&](size_t bytes) -> void* {
        void* r = base + off;
        off += (bytes + 511) & ~(size_t)511;
        return r;
    };
    float* dis = (float*)take((size_t)B * Nn * 4);
    int* cnt   = (int*)take((size_t)B * Nn * 4);
    int* rs    = (int*)take((size_t)B * Nn * 4);
    ushort_t* csr = (ushort_t*)take((size_t)B * nbkt * BKT_CAP * 2);
    int* bcur  = (int*)take((size_t)B * NBKT_MAX * 4);
    ushort_t* Wt1 = (ushort_t*)take(256 * 256 * 2);
    ushort_t* Wt2 = (ushort_t*)take(128 * 256 * 2);
    ushort_t* Wt3 = (ushort_t*)take(64 * 128 * 2);
    float* b1p = (float*)take(256 * 4);
    float* b2p = (float*)take(128 * 4);
    float* b3p = (float*)take(64 * 4);
    float* partial = (float*)take(((size_t)B * Nn / 16 + 64) * 4);
    size_t fixed = off;
    size_t abFull = ((size_t)B * Nn * 256 * 2 + 511) & ~(size_t)511;
    size_t hbFull = ((size_t)B * Nn * 256 + 511) & ~(size_t)511;
    const bool batched = ws_size >= fixed + abFull + hbFull;
    const int Bc = batched ? 3 : 1;
    ushort_t* Ab = (ushort_t*)take((size_t)Bc * Nn * 256 * 2);
    uchar_t* Hsh = (uchar_t*)take((size_t)Bc * Nn * 256);  // fp8: [.,256]/[.,128]/[.,64]

    // bucket record buffer aliases Ab (dead until after CSR build):
    // needs B*nbkt*BKT_CAP*4 = 14.45MB <= Ab (>=25.6MB even at Bc=1).
    uint_t* bkt = (uint_t*)Ab;

    IP3 ei = {EI[0], EI[1], EI[2]};
    const int nb_p1 = (E + P1_CH - 1) / P1_CH;

    // ---- prep + batched CSR build (all 3 graphs) ----
    zero_small_k<<<(B * nbkt + 255) / 256, 256, 0, stream>>>(bcur, B * nbkt);
    wt_all_k<<<(106944 + 255) / 256, 256, 0, stream>>>(
        W1, W2, W3, b1, b2, b3, Wt1, Wt2, Wt3, b1p, b2p, b3p);
    bucket_p1_k<<<dim3(nb_p1, 3), 256, 0, stream>>>(ei, E, nbkt, bcur, bkt);
    bucket_p2_k<<<dim3(nbkt, 3), 256, 0, stream>>>(bkt, bcur, csr, rs, cnt, dis, Nn, nbkt);

    // ---- layer pipeline (batched over Bc graphs per pass) ----
    const int Mp  = Bc * Nn;
    const int npb = (Mp + 63) / 64;            // gather_reduce blocks per pass
    for (int g0 = 0; g0 < B; g0 += Bc) {
        const int M = Mp;
        FP3 xp;
        if (Bc == 3) { xp.a = X[0]; xp.b = X[1]; xp.c = X[2]; }
        else         { xp.a = X[g0]; xp.b = X[g0]; xp.c = X[g0]; }
        const float* disl = dis + (size_t)g0 * Nn;
        const int*   rsl  = rs  + (size_t)g0 * Nn;
        const int*   cntl = cnt + (size_t)g0 * Nn;

        // L1: X fp32 [M,256] @ Wt1 -> Hsh fp8 [M,256] (permuted cols)
        gemm_mfma_k<2, 2, true, 256><<<dim3(2, (M + 127) / 128), 256, 0, stream>>>(
            xp, nullptr, Wt1, disl, Hsh, M, 256, Nn);
        gather_relu_k<256><<<(M + 15) / 16, 256, 0, stream>>>(
            Hsh, Ab, rsl, cntl, csr, disl, b1p, M, Nn);

        // L2: Ab bf16 [M,256](perm) @ Wt2(perm-k) -> Hsh fp8 [M,128](perm)
        gemm_mfma_k<2, 2, false, 256><<<dim3(1, (M + 127) / 128), 256, 0, stream>>>(
            xp, Ab, Wt2, disl, Hsh, M, 128, Nn);
        gather_relu_k<128><<<(M + 31) / 32, 256, 0, stream>>>(
            Hsh, Ab, rsl, cntl, csr, disl, b2p, M, Nn);

        // L3: Ab bf16 [M,128](perm) @ Wt3(perm-k) -> Hsh fp8 [M,64](perm)
        gemm_mfma_k<2, 1, false, 128><<<dim3(1, (M + 127) / 128), 128, 0, stream>>>(
            xp, Ab, Wt3, disl, Hsh, M, 64, Nn);
        gather_reduce_k<<<npb, 256, 0, stream>>>(
            Hsh, rsl, cntl, csr, disl, b3p, M, Nn, partial + (g0 / Bc) * npb);
    }
    reduce_partials_k<<<1, 1024, 0, stream>>>(partial, (B / Bc) * npb, out);
}

// Round 9
// 451.809 us; speedup vs baseline: 1.0474x; 1.0474x over previous
//
#include <hip/hip_runtime.h>
#include <hip/hip_bf16.h>

// ---------------------------------------------------------------------------
// GCN stack: 3 graphs x 3 layers (256->256->128->64), final scalar = sum/64.
// Math: with h' = (x@W) * dis[row],
//   out[i] = relu( dis[i] * (h'[i] + sum_{e: dst=i} h'[src[e]]) + b )
// R16: revert R15's L1 grid.x=2 split (doubled X fp32 fetch 83->151MB,
// 88->103us). L1 = R14 geometry (WM=2,WN=4, 512thr, X read once) + B staged
// via global_load_lds (only A's fp32->bf16 cvt remains on the sync path).
// R14: bf16 GEMMs (L2/L3) fully global_load_lds width-16, linear [row][32]
// LDS. R11: gather unroll-8 + uint2 CSR idx; bucket_p2 4-aligns CSR.
// R10: 16B dwordx4 gather loads. R8: 2-pass LDS counting-sort CSR build.
// ---------------------------------------------------------------------------

typedef unsigned short ushort_t;
typedef unsigned int uint_t;
typedef unsigned char uchar_t;
typedef __attribute__((ext_vector_type(8))) short v8s;   // 8 bf16
typedef __attribute__((ext_vector_type(4))) float v4f;   // MFMA accum
typedef __attribute__((ext_vector_type(2))) float v2f;

struct FP3 { const float* a; const float* b; const float* c; };
struct IP3 { const int* a; const int* b; const int* c; };

#define BKT_SHIFT 9            // 512 nodes per bucket
#define BKT_NODES 512
#define NBKT_MAX 128           // supports Nn <= 65536 (ushort csr constraint)
#define BKT_CAP 12288          // edge slots per bucket region (mean 8192 @ E=800k)
#define P1_CH 4096             // edges per pass-1 block

static __device__ __forceinline__ ushort_t f2bf(float f) {
    uint_t u = __float_as_uint(f);
    u += 0x7fffu + ((u >> 16) & 1u);   // RNE
    return (ushort_t)(u >> 16);
}
static __device__ __forceinline__ uint_t pack2(float a, float b) {
    return (uint_t)f2bf(a) | ((uint_t)f2bf(b) << 16);
}

// async 16B global->LDS (no VGPR round-trip); dest must be linear in lane order
static __device__ __forceinline__ void gload_lds16(const ushort_t* g, ushort_t* l) {
    __builtin_amdgcn_global_load_lds(g, l, 16, 0, 0);
}

// permutation within each 64-block: stored pos q holds actual col P64(q)
static __device__ __forceinline__ int P64(int q) {
    return (q & ~63) | (((q & 3) << 4) | ((q & 63) >> 2));
}

// fp8 e4m3fn encode, RNE, clamp (fallback path).
static __device__ __forceinline__ uint_t f2fp8(float f) {
    uint_t u = __float_as_uint(f);
    uint_t s = (u >> 24) & 0x80u;
    uint_t a = u & 0x7fffffffu;
    uint_t r;
    if (a >= 0x43E00000u) {
        r = 0x7Eu;
    } else if (a < 0x3C800000u) {
        r = (uint_t)(int)rintf(__uint_as_float(a) * 512.0f);
    } else {
        uint_t t = a + 0x7FFFFu + ((a >> 20) & 1u);
        r = (t >> 20) - 960u;
        if (r > 0x7Eu) r = 0x7Eu;
    }
    return s | r;
}
static __device__ __forceinline__ uint_t pack_fp8x4(float a, float b, float c, float d) {
#if __has_builtin(__builtin_amdgcn_cvt_pk_fp8_f32)
    int w = 0;
    w = __builtin_amdgcn_cvt_pk_fp8_f32(a, b, w, false);   // bytes 0,1
    w = __builtin_amdgcn_cvt_pk_fp8_f32(c, d, w, true);    // bytes 2,3
    return (uint_t)w;
#else
    return f2fp8(a) | (f2fp8(b) << 8) | (f2fp8(c) << 16) | (f2fp8(d) << 24);
#endif
}
static __device__ __forceinline__ float fp8f(uint_t b) {
    uint_t t = (b & 0x7Fu) << 20;
    float f = __uint_as_float(t) * 0x1.0p+120f;
    return __uint_as_float(__float_as_uint(f) | ((b & 0x80u) << 24));
}
static __device__ __forceinline__ float4 fp84cvt(uint_t w) {
    float4 f;
#if __has_builtin(__builtin_amdgcn_cvt_pk_f32_fp8)
    v2f lo = __builtin_amdgcn_cvt_pk_f32_fp8((int)w, false);
    v2f hi = __builtin_amdgcn_cvt_pk_f32_fp8((int)w, true);
    f.x = lo[0]; f.y = lo[1]; f.z = hi[0]; f.w = hi[1];
#else
    f.x = fp8f(w & 0xffu); f.y = fp8f((w >> 8) & 0xffu);
    f.z = fp8f((w >> 16) & 0xffu); f.w = fp8f(w >> 24);
#endif
    return f;
}
static __device__ __forceinline__ float4 load_fp84(const uchar_t* p) {
    return fp84cvt(*(const uint_t*)p);
}
// accumulate 16 fp8 (one uint4) into a[16]
static __device__ __forceinline__ void acc16(float* a, uint4 w) {
    float4 f;
    f = fp84cvt(w.x); a[0]+=f.x; a[1]+=f.y; a[2]+=f.z; a[3]+=f.w;
    f = fp84cvt(w.y); a[4]+=f.x; a[5]+=f.y; a[6]+=f.z; a[7]+=f.w;
    f = fp84cvt(w.z); a[8]+=f.x; a[9]+=f.y; a[10]+=f.z; a[11]+=f.w;
    f = fp84cvt(w.w); a[12]+=f.x; a[13]+=f.y; a[14]+=f.z; a[15]+=f.w;
}

// ---------------------------------------------------------------------------
__global__ __launch_bounds__(256) void zero_small_k(int* p, int n) {
    int i = blockIdx.x * 256 + threadIdx.x;
    if (i < n) p[i] = 0;
}

// Weight transpose+convert (Wt2/Wt3 k-permuted) + permuted bias copies.
__global__ __launch_bounds__(256) void wt_all_k(
    const float* __restrict__ W1, const float* __restrict__ W2, const float* __restrict__ W3,
    const float* __restrict__ b1, const float* __restrict__ b2, const float* __restrict__ b3,
    ushort_t* __restrict__ Wt1, ushort_t* __restrict__ Wt2, ushort_t* __restrict__ Wt3,
    float* __restrict__ b1p, float* __restrict__ b2p, float* __restrict__ b3p) {
    int i = blockIdx.x * 256 + threadIdx.x;
    if (i < 65536) {
        int k = i >> 8, n = i & 255;
        Wt1[n * 256 + k] = f2bf(W1[i]);            // A of GEMM-1 (X) unpermuted
    } else if (i < 98304) {
        int j = i - 65536; int k = j >> 7, n = j & 127;   // k' in [0,256)
        Wt2[n * 256 + k] = f2bf(W2[P64(k) * 128 + n]);
    } else if (i < 106496) {
        int j = i - 98304; int k = j >> 6, n = j & 63;    // k' in [0,128)
        Wt3[n * 128 + k] = f2bf(W3[P64(k) * 64 + n]);
    } else if (i < 106752) {
        int c = i - 106496; b1p[c] = b1[P64(c)];
    } else if (i < 106880) {
        int c = i - 106752; b2p[c] = b2[P64(c)];
    } else if (i < 106944) {
        int c = i - 106880; b3p[c] = b3[P64(c)];
    }
}

// ---------------------------------------------------------------------------
// Pass 1: LDS counting sort of a 4096-edge chunk by bucket (dst>>9), then
// coalesced run-writes into fixed-capacity bucket regions of bkt[].
// Record: src | dstlow<<16 | b<<25  (src<65536, dstlow<512, b<128).
// ---------------------------------------------------------------------------
__global__ __launch_bounds__(256) void bucket_p1_k(IP3 ei, int E, int nbkt,
    int* __restrict__ bcur, uint_t* __restrict__ bkt)
{
    int g = blockIdx.y;
    const int* eb = g == 0 ? ei.a : (g == 1 ? ei.b : ei.c);
    __shared__ uint_t srt[P1_CH];
    __shared__ int cntL[NBKT_MAX], offsL[NBKT_MAX], fillL[NBKT_MAX], gbaseL[NBKT_MAX];
    const int t = threadIdx.x;
    if (t < NBKT_MAX) { cntL[t] = 0; fillL[t] = 0; }
    __syncthreads();

    const int cb = blockIdx.x * P1_CH;
    const int ne = (cb + P1_CH <= E) ? P1_CH : (E - cb);
    uint_t rec[16];
    int rb[16];
    #pragma unroll
    for (int j = 0; j < 16; ++j) {
        int e = cb + j * 256 + t;
        rb[j] = -1;
        if (e < E) {
            int s = eb[e], d = eb[E + e];
            int b = d >> BKT_SHIFT;
            rb[j] = b;
            rec[j] = (uint_t)s | ((uint_t)(d & (BKT_NODES - 1)) << 16) | ((uint_t)b << 25);
            atomicAdd(&cntL[b], 1);
        }
    }
    __syncthreads();

    // exclusive scan over NBKT_MAX bins, wave 0 (2 bins/lane)
    if (t < 64) {
        int i0 = 2 * t, i1 = 2 * t + 1;
        int c0 = cntL[i0], c1 = cntL[i1];
        int s = c0 + c1, x = s;
        #pragma unroll
        for (int off = 1; off < 64; off <<= 1) {
            int y = __shfl_up(x, off);
            if (t >= off) x += y;
        }
        offsL[i0] = x - s;
        offsL[i1] = x - c1;
    }
    __syncthreads();
    if (t < nbkt) gbaseL[t] = atomicAdd(&bcur[g * nbkt + t], cntL[t]);
    __syncthreads();

    // scatter records into LDS-sorted order
    #pragma unroll
    for (int j = 0; j < 16; ++j) {
        if (rb[j] >= 0) {
            int p = offsL[rb[j]] + atomicAdd(&fillL[rb[j]], 1);
            srt[p] = rec[j];
        }
    }
    __syncthreads();

    // coalesced run-copy to global bucket regions
    for (int i = t; i < ne; i += 256) {
        uint_t r = srt[i];
        int b = r >> 25;
        int glob = gbaseL[b] + (i - offsL[b]);
        if (glob < BKT_CAP)
            bkt[((long)(g * nbkt + b)) * BKT_CAP + glob] = r;
    }
}

// ---------------------------------------------------------------------------
// Pass 2: one block per (graph,bucket). Count per-node degrees in LDS, block
// scan over CEIL4(cnt) so every node's CSR start is 4-ushort (8B) aligned
// (enables uint2 index loads in the gathers); emit rs/cnt/dis coalesced;
// stage the bucket's CSR segment in LDS and flush with uint4 stores.
// ---------------------------------------------------------------------------
__global__ __launch_bounds__(256) void bucket_p2_k(
    const uint_t* __restrict__ bkt, const int* __restrict__ bcur,
    ushort_t* __restrict__ csr, int* __restrict__ rs, int* __restrict__ cnt,
    float* __restrict__ dis, int Nn, int nbkt)
{
    const int b = blockIdx.x, g = blockIdx.y;
    const int r = g * nbkt + b;
    __shared__ __align__(16) ushort_t csrL[BKT_CAP];
    __shared__ int cntL[BKT_NODES], offsL[BKT_NODES], fillL[BKT_NODES];
    __shared__ int wsum[4];
    const int t = threadIdx.x;
    cntL[t] = 0; cntL[t + 256] = 0;
    fillL[t] = 0; fillL[t + 256] = 0;
    __syncthreads();

    int nE = bcur[r];
    if (nE > BKT_CAP) nE = BKT_CAP;
    const uint_t* src = bkt + (long)r * BKT_CAP;

    for (int i = t; i < nE; i += 256)
        atomicAdd(&cntL[(src[i] >> 16) & (BKT_NODES - 1)], 1);
    __syncthreads();

    // exclusive scan over 512 CEIL4'd counters (2/thread, adjacent pair)
    int c0 = cntL[2 * t], c1 = cntL[2 * t + 1];
    int a0 = (c0 + 3) & ~3, a1 = (c1 + 3) & ~3;
    int s = a0 + a1, x = s;
    const int lane = t & 63, wid = t >> 6;
    #pragma unroll
    for (int off = 1; off < 64; off <<= 1) {
        int y = __shfl_up(x, off);
        if (lane >= off) x += y;
    }
    if (lane == 63) wsum[wid] = x;
    __syncthreads();
    int we = 0;
    #pragma unroll
    for (int w = 0; w < 4; ++w) if (w < wid) we += wsum[w];
    x += we;
    offsL[2 * t] = x - s;
    offsL[2 * t + 1] = x - a1;
    const int padTot = wsum[0] + wsum[1] + wsum[2] + wsum[3];
    __syncthreads();

    // rs / cnt / dis (coalesced)
    const int rbase = r * BKT_CAP;
    for (int nl = t; nl < BKT_NODES; nl += 256) {
        int node = (b << BKT_SHIFT) + nl;
        if (node < Nn) {
            int gi = g * Nn + node;
            int c = cntL[nl];
            rs[gi] = rbase + offsL[nl];
            cnt[gi] = c;
            dis[gi] = rsqrtf((float)c + 1.0f);
        }
    }

    // build CSR segment in LDS (guard: pad may push past cap at ~40 sigma)
    for (int i = t; i < nE; i += 256) {
        uint_t rr = src[i];
        int dl = (rr >> 16) & (BKT_NODES - 1);
        int p = offsL[dl] + atomicAdd(&fillL[dl], 1);
        if (p < BKT_CAP) csrL[p] = (ushort_t)(rr & 0xffffu);
    }
    __syncthreads();

    // flush CSR segment coalesced (16B chunks over padded extent)
    ushort_t* dst = csr + (long)rbase;
    int nF = padTot < BKT_CAP ? padTot : BKT_CAP;
    int nF8 = (nF + 7) & ~7;
    if (nF8 > BKT_CAP) nF8 = BKT_CAP;
    for (int i = t * 8; i < nF8; i += 2048)
        *(uint4*)(dst + i) = *(const uint4*)(csrL + i);
}

// ---------------------------------------------------------------------------
// MFMA GEMM over M = Bc*Nn rows: H8[m][c'] = fp8(D[m][P64(c')] * dis[m]).
// AFP32 (L1): sync fp32->bf16 VGPR staging for A (LDA=40 pad); B staged via
// global_load_lds into linear [row][32] LDS. X read ONCE (grid.x = 1).
// bf16 (L2/L3): both A and B via global_load_lds, linear [row][32] LDS
// (chunk c at byte c*16 = wave-uniform base + lane*16).
// Direct permuted global store (C/D: col=lane&15, row=quad*4+reg).
// ---------------------------------------------------------------------------
template<int WM, int WN, bool AFP32, int K_>
__global__ __launch_bounds__(WM * WN * 64) void gemm_mfma_k(
    FP3 xp, const ushort_t* __restrict__ Ab,
    const ushort_t* __restrict__ Wt, const float* __restrict__ dis,
    uchar_t* __restrict__ out8, int M, int N, int Nn)
{
    constexpr int BM = WM * 64, BN = WN * 64, NT = WM * WN * 64;
    constexpr int LDA = AFP32 ? 40 : 32;   // A rows: pad (sync write) vs linear
    constexpr int LDB = 32;                // B rows: linear (gload_lds)
    constexpr int NCA = (BM * 4) / NT;     // 16B chunks per thread (A)
    constexpr int NCB = (BN * 4) / NT;     // 16B chunks per thread (B)
    __shared__ __align__(16) ushort_t As[BM * LDA];
    __shared__ __align__(16) ushort_t Bs[BN * LDB];

    const int tid  = threadIdx.x;
    const int lane = tid & 63;
    const int wave = tid >> 6;
    const int quad = lane >> 4, l16 = lane & 15;
    const int wm = wave / WN, wn = wave % WN;
    const int tile_m = blockIdx.y * BM, tile_n = blockIdx.x * BN;

    v4f acc[4][4];
    #pragma unroll
    for (int i = 0; i < 4; ++i)
        #pragma unroll
        for (int j = 0; j < 4; ++j)
            acc[i][j] = (v4f){0.f, 0.f, 0.f, 0.f};

    const float* Xrow[AFP32 ? NCA : 1];
    const int akc = (tid & 3) * 8;         // k-offset within 32-chunk (NT%4==0)
    if constexpr (AFP32) {
        #pragma unroll
        for (int i = 0; i < NCA; ++i) {
            int r = (tid >> 2) + i * (NT / 4);
            int gr = tile_m + r;
            Xrow[i] = nullptr;
            if (gr < M) {
                int lg = gr / Nn;
                int rl = gr - lg * Nn;
                const float* Xg = lg == 0 ? xp.a : (lg == 1 ? xp.b : xp.c);
                Xrow[i] = Xg + (long)rl * K_;
            }
        }
    }

    for (int k0 = 0; k0 < K_; k0 += 32) {
        if constexpr (AFP32) {
            #pragma unroll
            for (int i = 0; i < NCA; ++i) {
                int r = (tid >> 2) + i * (NT / 4);
                uint4 w = make_uint4(0, 0, 0, 0);
                if (Xrow[i]) {
                    float4 f0 = *(const float4*)(Xrow[i] + k0 + akc);
                    float4 f1 = *(const float4*)(Xrow[i] + k0 + akc + 4);
                    w.x = pack2(f0.x, f0.y); w.y = pack2(f0.z, f0.w);
                    w.z = pack2(f1.x, f1.y); w.w = pack2(f1.z, f1.w);
                }
                *(uint4*)&As[r * LDA + akc] = w;
            }
        } else {
            // async direct-to-LDS staging; OOB tail rows (<16) read allocated
            // workspace and only pollute never-stored acc rows.
            #pragma unroll
            for (int i = 0; i < NCA; ++i) {
                int cch = tid + i * NT;
                int r = cch >> 2, kc = (cch & 3) * 8;
                gload_lds16(Ab + (long)(tile_m + r) * K_ + k0 + kc, &As[cch * 8]);
            }
        }
        #pragma unroll
        for (int i = 0; i < NCB; ++i) {
            int cch = tid + i * NT;
            int r = cch >> 2, kc = (cch & 3) * 8;
            gload_lds16(Wt + (long)(tile_n + r) * K_ + k0 + kc, &Bs[cch * 8]);
        }
        __syncthreads();

        v8s a[4], b[4];
        #pragma unroll
        for (int f = 0; f < 4; ++f)
            a[f] = *(const v8s*)&As[(wm * 64 + f * 16 + l16) * LDA + quad * 8];
        #pragma unroll
        for (int f = 0; f < 4; ++f)
            b[f] = *(const v8s*)&Bs[(wn * 64 + f * 16 + l16) * LDB + quad * 8];
        #pragma unroll
        for (int i = 0; i < 4; ++i)
            #pragma unroll
            for (int j = 0; j < 4; ++j)
                acc[i][j] = __builtin_amdgcn_mfma_f32_16x16x32_bf16(a[i], b[j], acc[i][j], 0, 0, 0);
        __syncthreads();
    }

    #pragma unroll
    for (int i = 0; i < 4; ++i) {
        #pragma unroll
        for (int r = 0; r < 4; ++r) {
            int gr = tile_m + wm * 64 + i * 16 + quad * 4 + r;
            if (gr < M) {
                float s = dis[gr];
                uint_t w = pack_fp8x4(acc[i][0][r] * s, acc[i][1][r] * s,
                                      acc[i][2][r] * s, acc[i][3][r] * s);
                *(uint_t*)(out8 + (long)gr * N + tile_n + wn * 64 + l16 * 4) = w;
            }
        }
    }
}

// ---------------------------------------------------------------------------
// Gather + relu. L = F/16 lanes per node, 16B dwordx4 loads, unroll-8 with
// uint2 CSR index loads (node CSR starts are 8B-aligned by bucket_p2).
// OUT[i] = bf16(relu(dis[i]*(H[i] + sum_nbrs H[s]) + bp)); cols permuted.
// ---------------------------------------------------------------------------
template<int F>
__global__ __launch_bounds__(256) void gather_relu_k(
    const uchar_t* __restrict__ H8, ushort_t* __restrict__ OUT,
    const int* __restrict__ rs, const int* __restrict__ cnt,
    const ushort_t* __restrict__ csr, const float* __restrict__ dis,
    const float* __restrict__ bias, int n, int Nn)
{
    constexpr int L = F / 16;          // lanes per node
    constexpr int NPB = 256 / L;
    int node = blockIdx.x * NPB + threadIdx.x / L;
    if (node >= n) return;
    int c = (threadIdx.x % L) * 16;    // col base (fp8: 1 byte per col)
    int base = rs[node];
    int deg  = cnt[node];
    int lg   = node / Nn;
    const uchar_t* Hg = H8 + (long)lg * Nn * F;

    float a[16];
    {
        uint4 w = *(const uint4*)(H8 + (long)node * F + c);   // self-loop
        float4 f;
        f = fp84cvt(w.x); a[0]=f.x; a[1]=f.y; a[2]=f.z; a[3]=f.w;
        f = fp84cvt(w.y); a[4]=f.x; a[5]=f.y; a[6]=f.z; a[7]=f.w;
        f = fp84cvt(w.z); a[8]=f.x; a[9]=f.y; a[10]=f.z; a[11]=f.w;
        f = fp84cvt(w.w); a[12]=f.x; a[13]=f.y; a[14]=f.z; a[15]=f.w;
    }
    int k = 0;
    for (; k + 7 < deg; k += 8) {
        uint2 i0 = *(const uint2*)(csr + base + k);
        uint2 i1 = *(const uint2*)(csr + base + k + 4);
        int s0 = i0.x & 0xffff, s1 = i0.x >> 16;
        int s2 = i0.y & 0xffff, s3 = i0.y >> 16;
        int s4 = i1.x & 0xffff, s5 = i1.x >> 16;
        int s6 = i1.y & 0xffff, s7 = i1.y >> 16;
        uint4 w0 = *(const uint4*)(Hg + (long)s0 * F + c);
        uint4 w1 = *(const uint4*)(Hg + (long)s1 * F + c);
        uint4 w2 = *(const uint4*)(Hg + (long)s2 * F + c);
        uint4 w3 = *(const uint4*)(Hg + (long)s3 * F + c);
        uint4 w4 = *(const uint4*)(Hg + (long)s4 * F + c);
        uint4 w5 = *(const uint4*)(Hg + (long)s5 * F + c);
        uint4 w6 = *(const uint4*)(Hg + (long)s6 * F + c);
        uint4 w7 = *(const uint4*)(Hg + (long)s7 * F + c);
        acc16(a, w0); acc16(a, w1); acc16(a, w2); acc16(a, w3);
        acc16(a, w4); acc16(a, w5); acc16(a, w6); acc16(a, w7);
    }
    for (; k + 3 < deg; k += 4) {
        uint2 i0 = *(const uint2*)(csr + base + k);
        int s0 = i0.x & 0xffff, s1 = i0.x >> 16;
        int s2 = i0.y & 0xffff, s3 = i0.y >> 16;
        uint4 w0 = *(const uint4*)(Hg + (long)s0 * F + c);
        uint4 w1 = *(const uint4*)(Hg + (long)s1 * F + c);
        uint4 w2 = *(const uint4*)(Hg + (long)s2 * F + c);
        uint4 w3 = *(const uint4*)(Hg + (long)s3 * F + c);
        acc16(a, w0); acc16(a, w1); acc16(a, w2); acc16(a, w3);
    }
    for (; k < deg; ++k) {
        int s0 = csr[base + k];
        uint4 w0 = *(const uint4*)(Hg + (long)s0 * F + c);
        acc16(a, w0);
    }
    float di = dis[node];
    const float4* bp = (const float4*)(bias + c);
    float4 b0 = bp[0], b1 = bp[1], b2 = bp[2], b3 = bp[3];
    uint4 o0, o1;
    o0.x = pack2(fmaxf(fmaf(di, a[0],  b0.x), 0.f), fmaxf(fmaf(di, a[1],  b0.y), 0.f));
    o0.y = pack2(fmaxf(fmaf(di, a[2],  b0.z), 0.f), fmaxf(fmaf(di, a[3],  b0.w), 0.f));
    o0.z = pack2(fmaxf(fmaf(di, a[4],  b1.x), 0.f), fmaxf(fmaf(di, a[5],  b1.y), 0.f));
    o0.w = pack2(fmaxf(fmaf(di, a[6],  b1.z), 0.f), fmaxf(fmaf(di, a[7],  b1.w), 0.f));
    o1.x = pack2(fmaxf(fmaf(di, a[8],  b2.x), 0.f), fmaxf(fmaf(di, a[9],  b2.y), 0.f));
    o1.y = pack2(fmaxf(fmaf(di, a[10], b2.z), 0.f), fmaxf(fmaf(di, a[11], b2.w), 0.f));
    o1.z = pack2(fmaxf(fmaf(di, a[12], b3.x), 0.f), fmaxf(fmaf(di, a[13], b3.y), 0.f));
    o1.w = pack2(fmaxf(fmaf(di, a[14], b3.z), 0.f), fmaxf(fmaf(di, a[15], b3.w), 0.f));
    ushort_t* orow = OUT + (long)node * F + c;
    *(uint4*)(orow) = o0;
    *(uint4*)(orow + 8) = o1;
}

// Layer-3: gather + relu + per-block partial sum (permutation-invariant).
// F=64: L=4 lanes/node, 64 nodes/block, unroll-8.
__global__ __launch_bounds__(256) void gather_reduce_k(
    const uchar_t* __restrict__ H8,
    const int* __restrict__ rs, const int* __restrict__ cnt,
    const ushort_t* __restrict__ csr, const float* __restrict__ dis,
    const float* __restrict__ bias, int n, int Nn, float* __restrict__ partial)
{
    constexpr int F = 64, L = 4, NPB = 64;
    int node = blockIdx.x * NPB + threadIdx.x / L;
    int c = (threadIdx.x % L) * 16;
    float val = 0.f;
    if (node < n) {
        int lg = node / Nn;
        const uchar_t* Hg = H8 + (long)lg * Nn * F;
        float a[16];
        {
            uint4 w = *(const uint4*)(H8 + (long)node * F + c);
            float4 f;
            f = fp84cvt(w.x); a[0]=f.x; a[1]=f.y; a[2]=f.z; a[3]=f.w;
            f = fp84cvt(w.y); a[4]=f.x; a[5]=f.y; a[6]=f.z; a[7]=f.w;
            f = fp84cvt(w.z); a[8]=f.x; a[9]=f.y; a[10]=f.z; a[11]=f.w;
            f = fp84cvt(w.w); a[12]=f.x; a[13]=f.y; a[14]=f.z; a[15]=f.w;
        }
        int base = rs[node], deg = cnt[node];
        int k = 0;
        for (; k + 7 < deg; k += 8) {
            uint2 i0 = *(const uint2*)(csr + base + k);
            uint2 i1 = *(const uint2*)(csr + base + k + 4);
            int s0 = i0.x & 0xffff, s1 = i0.x >> 16;
            int s2 = i0.y & 0xffff, s3 = i0.y >> 16;
            int s4 = i1.x & 0xffff, s5 = i1.x >> 16;
            int s6 = i1.y & 0xffff, s7 = i1.y >> 16;
            uint4 w0 = *(const uint4*)(Hg + (long)s0 * F + c);
            uint4 w1 = *(const uint4*)(Hg + (long)s1 * F + c);
            uint4 w2 = *(const uint4*)(Hg + (long)s2 * F + c);
            uint4 w3 = *(const uint4*)(Hg + (long)s3 * F + c);
            uint4 w4 = *(const uint4*)(Hg + (long)s4 * F + c);
            uint4 w5 = *(const uint4*)(Hg + (long)s5 * F + c);
            uint4 w6 = *(const uint4*)(Hg + (long)s6 * F + c);
            uint4 w7 = *(const uint4*)(Hg + (long)s7 * F + c);
            acc16(a, w0); acc16(a, w1); acc16(a, w2); acc16(a, w3);
            acc16(a, w4); acc16(a, w5); acc16(a, w6); acc16(a, w7);
        }
        for (; k + 3 < deg; k += 4) {
            uint2 i0 = *(const uint2*)(csr + base + k);
            int s0 = i0.x & 0xffff, s1 = i0.x >> 16;
            int s2 = i0.y & 0xffff, s3 = i0.y >> 16;
            uint4 w0 = *(const uint4*)(Hg + (long)s0 * F + c);
            uint4 w1 = *(const uint4*)(Hg + (long)s1 * F + c);
            uint4 w2 = *(const uint4*)(Hg + (long)s2 * F + c);
            uint4 w3 = *(const uint4*)(Hg + (long)s3 * F + c);
            acc16(a, w0); acc16(a, w1); acc16(a, w2); acc16(a, w3);
        }
        for (; k < deg; ++k) {
            int s0 = csr[base + k];
            uint4 w0 = *(const uint4*)(Hg + (long)s0 * F + c);
            acc16(a, w0);
        }
        float di = dis[node];
        const float4* bp = (const float4*)(bias + c);
        float4 b0 = bp[0], b1 = bp[1], b2 = bp[2], b3 = bp[3];
        val  = fmaxf(fmaf(di, a[0],  b0.x), 0.f) + fmaxf(fmaf(di, a[1],  b0.y), 0.f)
             + fmaxf(fmaf(di, a[2],  b0.z), 0.f) + fmaxf(fmaf(di, a[3],  b0.w), 0.f)
             + fmaxf(fmaf(di, a[4],  b1.x), 0.f) + fmaxf(fmaf(di, a[5],  b1.y), 0.f)
             + fmaxf(fmaf(di, a[6],  b1.z), 0.f) + fmaxf(fmaf(di, a[7],  b1.w), 0.f)
             + fmaxf(fmaf(di, a[8],  b2.x), 0.f) + fmaxf(fmaf(di, a[9],  b2.y), 0.f)
             + fmaxf(fmaf(di, a[10], b2.z), 0.f) + fmaxf(fmaf(di, a[11], b2.w), 0.f)
             + fmaxf(fmaf(di, a[12], b3.x), 0.f) + fmaxf(fmaf(di, a[13], b3.y), 0.f)
             + fmaxf(fmaf(di, a[14], b3.z), 0.f) + fmaxf(fmaf(di, a[15], b3.w), 0.f);
    }
    #pragma unroll
    for (int off = 32; off > 0; off >>= 1) val += __shfl_down(val, off);
    __shared__ float wsum[4];
    int lane = threadIdx.x & 63, wid = threadIdx.x >> 6;
    if (lane == 0) wsum[wid] = val;
    __syncthreads();
    if (threadIdx.x == 0)
        partial[blockIdx.x] = wsum[0] + wsum[1] + wsum[2] + wsum[3];
}

__global__ __launch_bounds__(1024) void reduce_partials_k(
    const float* __restrict__ partial, int npart, float* __restrict__ out)
{
    float s = 0.f;
    for (int i = threadIdx.x; i < npart; i += 1024) s += partial[i];
    #pragma unroll
    for (int off = 32; off > 0; off >>= 1) s += __shfl_down(s, off);
    __shared__ float wsum[16];
    int lane = threadIdx.x & 63, wid = threadIdx.x >> 6;
    if (lane == 0) wsum[wid] = s;
    __syncthreads();
    if (threadIdx.x == 0) {
        float t = 0.f;
        #pragma unroll
        for (int w = 0; w < 16; ++w) t += wsum[w];
        out[0] = t * (1.0f / 64.0f);
    }
}

extern "C" void kernel_launch(void* const* d_in, const int* in_sizes, int n_in,
                              void* d_out, int out_size, void* d_ws, size_t ws_size,
                              hipStream_t stream) {
    const float* X[3]  = {(const float*)d_in[0], (const float*)d_in[1], (const float*)d_in[2]};
    const int*   EI[3] = {(const int*)d_in[3], (const int*)d_in[4], (const int*)d_in[5]};
    const float* W1 = (const float*)d_in[6];
    const float* b1 = (const float*)d_in[7];
    const float* W2 = (const float*)d_in[8];
    const float* b2 = (const float*)d_in[9];
    const float* W3 = (const float*)d_in[10];
    const float* b3 = (const float*)d_in[11];
    float* out = (float*)d_out;

    const int Nn = in_sizes[0] / 256;   // 50000 (< 65536 for ushort csr)
    const int E  = in_sizes[3] / 2;     // 800000
    const int B  = 3;
    const int nbkt = (Nn + BKT_NODES - 1) >> BKT_SHIFT;   // 98

    // ---- workspace layout (512B-aligned regions) ----
    char* base = (char*)d_ws;
    size_t off = 0;
    auto take = [&](size_t bytes) -> void* {
        void* r = base + off;
        off += (bytes + 511) & ~(size_t)511;
        return r;
    };
    float* dis = (float*)take((size_t)B * Nn * 4);
    int* cnt   = (int*)take((size_t)B * Nn * 4);
    int* rs    = (int*)take((size_t)B * Nn * 4);
    ushort_t* csr = (ushort_t*)take((size_t)B * nbkt * BKT_CAP * 2);
    int* bcur  = (int*)take((size_t)B * NBKT_MAX * 4);
    ushort_t* Wt1 = (ushort_t*)take(256 * 256 * 2);
    ushort_t* Wt2 = (ushort_t*)take(128 * 256 * 2);
    ushort_t* Wt3 = (ushort_t*)take(64 * 128 * 2);
    float* b1p = (float*)take(256 * 4);
    float* b2p = (float*)take(128 * 4);
    float* b3p = (float*)take(64 * 4);
    float* partial = (float*)take(((size_t)B * Nn / 16 + 64) * 4);
    size_t fixed = off;
    size_t abFull = ((size_t)B * Nn * 256 * 2 + 511) & ~(size_t)511;
    size_t hbFull = ((size_t)B * Nn * 256 + 511) & ~(size_t)511;
    const bool batched = ws_size >= fixed + abFull + hbFull;
    const int Bc = batched ? 3 : 1;
    ushort_t* Ab = (ushort_t*)take((size_t)Bc * Nn * 256 * 2);
    uchar_t* Hsh = (uchar_t*)take((size_t)Bc * Nn * 256);  // fp8: [.,256]/[.,128]/[.,64]

    // bucket record buffer aliases Ab (dead until after CSR build):
    // needs B*nbkt*BKT_CAP*4 = 14.45MB <= Ab (>=25.6MB even at Bc=1).
    uint_t* bkt = (uint_t*)Ab;

    IP3 ei = {EI[0], EI[1], EI[2]};
    const int nb_p1 = (E + P1_CH - 1) / P1_CH;

    // ---- prep + batched CSR build (all 3 graphs) ----
    zero_small_k<<<(B * nbkt + 255) / 256, 256, 0, stream>>>(bcur, B * nbkt);
    wt_all_k<<<(106944 + 255) / 256, 256, 0, stream>>>(
        W1, W2, W3, b1, b2, b3, Wt1, Wt2, Wt3, b1p, b2p, b3p);
    bucket_p1_k<<<dim3(nb_p1, 3), 256, 0, stream>>>(ei, E, nbkt, bcur, bkt);
    bucket_p2_k<<<dim3(nbkt, 3), 256, 0, stream>>>(bkt, bcur, csr, rs, cnt, dis, Nn, nbkt);

    // ---- layer pipeline (batched over Bc graphs per pass) ----
    const int Mp  = Bc * Nn;
    const int npb = (Mp + 63) / 64;            // gather_reduce blocks per pass
    for (int g0 = 0; g0 < B; g0 += Bc) {
        const int M = Mp;
        FP3 xp;
        if (Bc == 3) { xp.a = X[0]; xp.b = X[1]; xp.c = X[2]; }
        else         { xp.a = X[g0]; xp.b = X[g0]; xp.c = X[g0]; }
        const float* disl = dis + (size_t)g0 * Nn;
        const int*   rsl  = rs  + (size_t)g0 * Nn;
        const int*   cntl = cnt + (size_t)g0 * Nn;

        // L1: X fp32 [M,256] @ Wt1 -> Hsh fp8 [M,256] (permuted cols)
        gemm_mfma_k<2, 4, true, 256><<<dim3(1, (M + 127) / 128), 512, 0, stream>>>(
            xp, nullptr, Wt1, disl, Hsh, M, 256, Nn);
        gather_relu_k<256><<<(M + 15) / 16, 256, 0, stream>>>(
            Hsh, Ab, rsl, cntl, csr, disl, b1p, M, Nn);

        // L2: Ab bf16 [M,256](perm) @ Wt2(perm-k) -> Hsh fp8 [M,128](perm)
        gemm_mfma_k<2, 2, false, 256><<<dim3(1, (M + 127) / 128), 256, 0, stream>>>(
            xp, Ab, Wt2, disl, Hsh, M, 128, Nn);
        gather_relu_k<128><<<(M + 31) / 32, 256, 0, stream>>>(
            Hsh, Ab, rsl, cntl, csr, disl, b2p, M, Nn);

        // L3: Ab bf16 [M,128](perm) @ Wt3(perm-k) -> Hsh fp8 [M,64](perm)
        gemm_mfma_k<2, 1, false, 128><<<dim3(1, (M + 127) / 128), 128, 0, stream>>>(
            xp, Ab, Wt3, disl, Hsh, M, 64, Nn);
        gather_reduce_k<<<npb, 256, 0, stream>>>(
            Hsh, rsl, cntl, csr, disl, b3p, M, Nn, partial + (g0 / Bc) * npb);
    }
    reduce_partials_k<<<1, 1024, 0, stream>>>(partial, (B / Bc) * npb, out);
}